// Round 1
// baseline (210.111 us; speedup 1.0000x reference)
//
#include <hip/hip_runtime.h>

#define NIMG 8
#define IMH 2048
#define IMW 2048
#define GH 8
#define GW 8
#define TH 256
#define TW 256
#define NBINS 256
#define NTPI 64                        // tiles per image
#define CLIP_MAXF 256.0f               // clip_limit*pixels//NBINS = 65536//256
#define LUT_SCALE 0.0038909912109375f  // 255/65536, exact in f32
#define LOG_GAIN_F 2.5f

// ---- ordered-uint encoding for float atomic min/max ----
__device__ __forceinline__ unsigned fkey(float f) {
    unsigned b = __float_as_uint(f);
    return (b & 0x80000000u) ? ~b : (b | 0x80000000u);
}
__device__ __forceinline__ float funkey(unsigned u) {
    unsigned b = (u & 0x80000000u) ? (u & 0x7fffffffu) : ~u;
    return __uint_as_float(b);
}

__device__ __forceinline__ int pix_bin(float v, float mn, float den) {
    float xn = (v - mn) / den;                    // matches ref division
    float t  = LOG_GAIN_F * log2f(1.0f + xn);
    float xc = fminf(fmaxf(t, 0.0f), 1.0f);
    int b = (int)(xc * 256.0f);                   // trunc toward zero like astype(int32)
    return min(max(b, 0), 255);
}

// ---- K0: init the 4 atomic scalars ----
__global__ void k_init(unsigned* sc) {
    if (threadIdx.x == 0) {
        sc[0] = 0xFFFFFFFFu;  // input min
        sc[1] = 0u;           // input max
        sc[2] = 0xFFFFFFFFu;  // v min
        sc[3] = 0u;           // v max
    }
}

// ---- K1: global min/max of input ----
__global__ __launch_bounds__(256) void k_minmax_in(const float4* __restrict__ x,
                                                   unsigned* __restrict__ sc, int n4) {
    float mn = 3.4e38f, mx = -3.4e38f;
    int stride = gridDim.x * blockDim.x;
    for (int i = blockIdx.x * blockDim.x + threadIdx.x; i < n4; i += stride) {
        float4 v = x[i];
        mn = fminf(mn, fminf(fminf(v.x, v.y), fminf(v.z, v.w)));
        mx = fmaxf(mx, fmaxf(fmaxf(v.x, v.y), fmaxf(v.z, v.w)));
    }
#pragma unroll
    for (int m = 32; m >= 1; m >>= 1) {
        mn = fminf(mn, __shfl_xor(mn, m, 64));
        mx = fmaxf(mx, __shfl_xor(mx, m, 64));
    }
    __shared__ float smn[4], smx[4];
    int wid = threadIdx.x >> 6, lid = threadIdx.x & 63;
    if (lid == 0) { smn[wid] = mn; smx[wid] = mx; }
    __syncthreads();
    if (threadIdx.x == 0) {
#pragma unroll
        for (int i = 1; i < 4; i++) { mn = fminf(mn, smn[i]); mx = fmaxf(mx, smx[i]); }
        atomicMin(&sc[0], fkey(mn));
        atomicMax(&sc[1], fkey(mx));
    }
}

// ---- K2: per-pixel bin + per-tile histogram (one block per 256x256 tile) ----
// 512 threads: 8 rows per iteration, 32 iterations. Hot bin 255 (~68% of pixels
// due to log saturation) counted via ballot, not LDS atomic.
template <bool STOREBINS>
__global__ __launch_bounds__(512) void k_hist(const float* __restrict__ x,
                                              const unsigned* __restrict__ sc,
                                              float* __restrict__ hist,
                                              uchar4* __restrict__ bins) {
    __shared__ unsigned sh[NBINS];
    int t = threadIdx.x;
    if (t < NBINS) sh[t] = 0u;
    __syncthreads();

    int tile = blockIdx.x;  // 0..63
    int img  = blockIdx.y;  // 0..7
    int ty = tile >> 3, tx = tile & 7;
    float mn = funkey(sc[0]), mx = funkey(sc[1]);
    float den = mx - mn;

    size_t base = ((size_t)img * IMH + (size_t)ty * TH) * IMW + (size_t)tx * TW;
    const float* xt = x + base;
    int lid = t & 63;
    int rowoff = t >> 6;   // 0..7
    int c4 = t & 63;       // 0..63 float4 columns

    for (int it = 0; it < 32; ++it) {
        int r = (it << 3) + rowoff;
        float4 v = *(const float4*)(xt + (size_t)r * IMW + (c4 << 2));
        int b[4];
        b[0] = pix_bin(v.x, mn, den);
        b[1] = pix_bin(v.y, mn, den);
        b[2] = pix_bin(v.z, mn, den);
        b[3] = pix_bin(v.w, mn, den);
#pragma unroll
        for (int j = 0; j < 4; j++) {
            bool hot = (b[j] == 255);
            unsigned long long m = __ballot(hot);
            if (!hot) atomicAdd(&sh[b[j]], 1u);
            if (lid == 0 && m) atomicAdd(&sh[255], (unsigned)__popcll(m));
        }
        if (STOREBINS) {
            uchar4 q;
            q.x = (unsigned char)b[0]; q.y = (unsigned char)b[1];
            q.z = (unsigned char)b[2]; q.w = (unsigned char)b[3];
            bins[(base + (size_t)r * IMW + (size_t)(c4 << 2)) >> 2] = q;
        }
    }
    __syncthreads();
    if (t < NBINS)
        hist[((size_t)img * NTPI + tile) * NBINS + t] = (float)sh[t];
}

// ---- K3: clip + redistribute + cumsum -> LUT (one block per tile) ----
__global__ __launch_bounds__(256) void k_lut(const float* __restrict__ hist,
                                             float* __restrict__ lut) {
    int t = threadIdx.x;
    int tile = blockIdx.x;
    float h = hist[(size_t)tile * NBINS + t];
    float ex = fmaxf(h - CLIP_MAXF, 0.0f);

    // block reduce sum of excess (all values integer -> exact in f32)
    float s = ex;
#pragma unroll
    for (int m = 1; m < 64; m <<= 1) s += __shfl_xor(s, m, 64);
    __shared__ float wpart[4];
    int wid = t >> 6, lid = t & 63;
    if (lid == 0) wpart[wid] = s;
    __syncthreads();
    float excess = wpart[0] + wpart[1] + wpart[2] + wpart[3];

    h = fminf(h, CLIP_MAXF);
    float redist   = floorf(excess * (1.0f / 256.0f));  // /256 exact
    float residual = excess - redist * 256.0f;
    h = h + redist + (((float)t < residual) ? 1.0f : 0.0f);

    // inclusive block scan of h over 256 bins
    float c = h;
#pragma unroll
    for (int m = 1; m < 64; m <<= 1) {
        float o = __shfl_up(c, m, 64);
        if (lid >= m) c += o;
    }
    __shared__ float wsum[4];
    if (lid == 63) wsum[wid] = c;
    __syncthreads();
    float off = 0.0f;
    for (int i = 0; i < wid; i++) off += wsum[i];
    c += off;

    float l = fminf(floorf(c * LUT_SCALE), 255.0f);
    l = fmaxf(l, 0.0f);
    lut[(size_t)tile * NBINS + t] = l;
}

// ---- K4/K5: per-quadrant (128x128) bilinear LUT application ----
// FINAL=false: reduce v min/max.  FINAL=true: write normalized output.
template <bool USE_BINS, bool FINAL>
__global__ __launch_bounds__(256) void k_apply(const uchar4* __restrict__ bins,
                                               const float* __restrict__ x,
                                               const float* __restrict__ lut,
                                               unsigned* __restrict__ sc,
                                               float4* __restrict__ out) {
    __shared__ float L[4][NBINS];
    int t = threadIdx.x;
    int qx = blockIdx.x, qy = blockIdx.y, img = blockIdx.z;
    int ty = qy >> 1, tx = qx >> 1;
    int yA = (qy & 1) ? ty : max(ty - 1, 0);
    int yB = (qy & 1) ? min(ty + 1, GH - 1) : ty;
    int xA = (qx & 1) ? tx : max(tx - 1, 0);
    int xB = (qx & 1) ? min(tx + 1, GW - 1) : tx;

    const float* lb = lut + (size_t)img * NTPI * NBINS;
    L[0][t] = lb[(size_t)(yA * GW + xA) * NBINS + t];
    L[1][t] = lb[(size_t)(yA * GW + xB) * NBINS + t];
    L[2][t] = lb[(size_t)(yB * GW + xA) * NBINS + t];
    L[3][t] = lb[(size_t)(yB * GW + xB) * NBINS + t];
    __syncthreads();

    float mn = 0.f, den = 1.f;
    if (!USE_BINS) { mn = funkey(sc[0]); den = funkey(sc[1]) - mn; }
    float pmn = 0.f, oscale = 1.f;
    if (FINAL) {
        float vmn = funkey(sc[2]), vmx = funkey(sc[3]);
        pmn = vmn * (1.0f / 255.0f);
        float pmx = vmx * (1.0f / 255.0f);
        oscale = 1.0f / (pmx - pmn);
    }

    float vmnl = 3.4e38f, vmxl = -3.4e38f;
    int gy0 = qy << 7, gx0 = qx << 7;
    int rowoff = t >> 5;  // 0..7
    int c4 = t & 31;      // 0..31 (4-pixel groups across 128 cols)

    for (int it = 0; it < 16; ++it) {
        int r = (it << 3) + rowoff;
        int iy = gy0 + r;
        int ix0 = gx0 + (c4 << 2);
        size_t pidx = ((size_t)img * IMH + iy) * IMW + ix0;

        int b[4];
        if (USE_BINS) {
            uchar4 q = bins[pidx >> 2];
            b[0] = q.x; b[1] = q.y; b[2] = q.z; b[3] = q.w;
        } else {
            float4 v = *(const float4*)(x + pidx);
            b[0] = pix_bin(v.x, mn, den);
            b[1] = pix_bin(v.y, mn, den);
            b[2] = pix_bin(v.z, mn, den);
            b[3] = pix_bin(v.w, mn, den);
        }

        float tyf = ((float)iy + 0.5f) * (1.0f / 256.0f) - 0.5f;  // exact
        float wy = tyf - floorf(tyf);
        float4 o;
        float* op = &o.x;
#pragma unroll
        for (int j = 0; j < 4; j++) {
            float txf = ((float)(ix0 + j) + 0.5f) * (1.0f / 256.0f) - 0.5f;
            float wx = txf - floorf(txf);
            float g00 = L[0][b[j]], g01 = L[1][b[j]];
            float g10 = L[2][b[j]], g11 = L[3][b[j]];
            float v = (1.0f - wy) * ((1.0f - wx) * g00 + wx * g01) +
                      wy * ((1.0f - wx) * g10 + wx * g11);
            if (FINAL) {
                float p = v * (1.0f / 255.0f);
                op[j] = (p - pmn) * oscale;
            } else {
                vmnl = fminf(vmnl, v);
                vmxl = fmaxf(vmxl, v);
            }
        }
        if (FINAL) out[pidx >> 2] = o;
    }

    if (!FINAL) {
#pragma unroll
        for (int m = 32; m >= 1; m >>= 1) {
            vmnl = fminf(vmnl, __shfl_xor(vmnl, m, 64));
            vmxl = fmaxf(vmxl, __shfl_xor(vmxl, m, 64));
        }
        __shared__ float smn[4], smx[4];
        int wid = t >> 6, lid = t & 63;
        if (lid == 0) { smn[wid] = vmnl; smx[wid] = vmxl; }
        __syncthreads();
        if (t == 0) {
#pragma unroll
            for (int i = 1; i < 4; i++) { vmnl = fminf(vmnl, smn[i]); vmxl = fmaxf(vmxl, smx[i]); }
            atomicMin(&sc[2], fkey(vmnl));
            atomicMax(&sc[3], fkey(vmxl));
        }
    }
}

extern "C" void kernel_launch(void* const* d_in, const int* in_sizes, int n_in,
                              void* d_out, int out_size, void* d_ws, size_t ws_size,
                              hipStream_t stream) {
    const float* x = (const float*)d_in[0];
    float4* out = (float4*)d_out;

    unsigned char* ws = (unsigned char*)d_ws;
    unsigned* sc = (unsigned*)ws;                          // 64 B reserved
    float* hist  = (float*)(ws + 64);                      // 512 KB
    float* lut   = (float*)(ws + 64 + 512 * 1024);         // 512 KB
    uchar4* bins = (uchar4*)(ws + 64 + 1024 * 1024);       // 32 MB

    size_t need_bins = 64 + 1024 * 1024 + (size_t)NIMG * IMH * IMW;
    bool use_bins = (ws_size >= need_bins);

    k_init<<<dim3(1), dim3(64), 0, stream>>>(sc);

    int n4 = (NIMG * IMH * IMW) / 4;
    k_minmax_in<<<dim3(2048), dim3(256), 0, stream>>>((const float4*)x, sc, n4);

    if (use_bins)
        k_hist<true><<<dim3(NTPI, NIMG), dim3(512), 0, stream>>>(x, sc, hist, bins);
    else
        k_hist<false><<<dim3(NTPI, NIMG), dim3(512), 0, stream>>>(x, sc, hist, bins);

    k_lut<<<dim3(NIMG * NTPI), dim3(256), 0, stream>>>(hist, lut);

    dim3 qgrid(16, 16, NIMG);
    if (use_bins) {
        k_apply<true, false><<<qgrid, dim3(256), 0, stream>>>(bins, x, lut, sc, out);
        k_apply<true, true><<<qgrid, dim3(256), 0, stream>>>(bins, x, lut, sc, out);
    } else {
        k_apply<false, false><<<qgrid, dim3(256), 0, stream>>>(bins, x, lut, sc, out);
        k_apply<false, true><<<qgrid, dim3(256), 0, stream>>>(bins, x, lut, sc, out);
    }
}

// Round 2
// 127.432 us; speedup vs baseline: 1.6488x; 1.6488x over previous
//
#include <hip/hip_runtime.h>

#define NIMG 8
#define IMH 2048
#define IMW 2048
#define GH 8
#define GW 8
#define TH 256
#define TW 256
#define NBINS 256
#define NTPI 64                        // tiles per image
#define CLIP_MAXF 256.0f               // clip_limit*pixels//NBINS = 65536//256
#define LUT_SCALE 0.0038909912109375f  // 255/65536, exact in f32
#define LOG_GAIN_F 2.5f

#define MM_BLOCKS 1024                 // k_minmax_in grid
#define APPLY_BLOCKS (16 * 16 * NIMG)  // 2048 quadrant blocks

__device__ __forceinline__ int pix_bin(float v, float mn, float den) {
    float xn = (v - mn) / den;                    // matches ref division
    float t  = LOG_GAIN_F * log2f(1.0f + xn);
    float xc = fminf(fmaxf(t, 0.0f), 1.0f);
    int b = (int)(xc * 256.0f);                   // trunc toward zero like astype(int32)
    return min(max(b, 0), 255);
}

__device__ __forceinline__ void mm4(float4 v, float& mn, float& mx) {
    mn = fminf(mn, fminf(fminf(v.x, v.y), fminf(v.z, v.w)));
    mx = fmaxf(mx, fmaxf(fmaxf(v.x, v.y), fmaxf(v.z, v.w)));
}

// block-level min/max reduce; returns valid in thread 0
template <int NWAVES>
__device__ __forceinline__ void block_minmax(float& mn, float& mx, int t) {
#pragma unroll
    for (int m = 32; m >= 1; m >>= 1) {
        mn = fminf(mn, __shfl_xor(mn, m, 64));
        mx = fmaxf(mx, __shfl_xor(mx, m, 64));
    }
    __shared__ float smn[NWAVES], smx[NWAVES];
    int wid = t >> 6, lid = t & 63;
    if (lid == 0) { smn[wid] = mn; smx[wid] = mx; }
    __syncthreads();
    if (t == 0) {
#pragma unroll
        for (int i = 1; i < NWAVES; i++) { mn = fminf(mn, smn[i]); mx = fmaxf(mx, smx[i]); }
    }
}

// ---- K1: per-block min/max of input (block-contiguous 128KB chunk, 4 loads in flight) ----
__global__ __launch_bounds__(256) void k_minmax_in(const float4* __restrict__ x,
                                                   float2* __restrict__ red) {
    int t = threadIdx.x;
    size_t base = (size_t)blockIdx.x * 8192 + t;   // 8192 float4 per block
    float mn = 3.4e38f, mx = -3.4e38f;
#pragma unroll
    for (int k = 0; k < 32; k += 4) {
        float4 v0 = x[base + (size_t)(k + 0) * 256];
        float4 v1 = x[base + (size_t)(k + 1) * 256];
        float4 v2 = x[base + (size_t)(k + 2) * 256];
        float4 v3 = x[base + (size_t)(k + 3) * 256];
        mm4(v0, mn, mx); mm4(v1, mn, mx); mm4(v2, mn, mx); mm4(v3, mn, mx);
    }
    block_minmax<4>(mn, mx, t);
    if (t == 0) red[blockIdx.x] = make_float2(mn, mx);
}

// ---- K1r/K4r: single-block reduce of n float2 partials -> sc[slot], sc[slot+1] ----
__global__ __launch_bounds__(256) void k_reduce_minmax(const float2* __restrict__ red, int n,
                                                       float* __restrict__ sc, int slot) {
    int t = threadIdx.x;
    float mn = 3.4e38f, mx = -3.4e38f;
    for (int i = t; i < n; i += 256) {
        float2 p = red[i];
        mn = fminf(mn, p.x);
        mx = fmaxf(mx, p.y);
    }
    block_minmax<4>(mn, mx, t);
    if (t == 0) { sc[slot] = mn; sc[slot + 1] = mx; }
}

// ---- K2: per-pixel bin + per-tile histogram (one block per 256x256 tile) ----
// Hot bin 255 (~68% of pixels due to log saturation) counted via ballot, not LDS atomic.
template <bool STOREBINS>
__global__ __launch_bounds__(512) void k_hist(const float* __restrict__ x,
                                              const float* __restrict__ sc,
                                              float* __restrict__ hist,
                                              uchar4* __restrict__ bins) {
    __shared__ unsigned sh[NBINS];
    int t = threadIdx.x;
    if (t < NBINS) sh[t] = 0u;
    __syncthreads();

    int tile = blockIdx.x;  // 0..63
    int img  = blockIdx.y;  // 0..7
    int ty = tile >> 3, tx = tile & 7;
    float mn = sc[0], mx = sc[1];
    float den = mx - mn;

    size_t base = ((size_t)img * IMH + (size_t)ty * TH) * IMW + (size_t)tx * TW;
    const float* xt = x + base;
    int lid = t & 63;
    int rowoff = t >> 6;   // 0..7
    int c4 = t & 63;       // 0..63 float4 columns

    for (int it = 0; it < 32; ++it) {
        int r = (it << 3) + rowoff;
        float4 v = *(const float4*)(xt + (size_t)r * IMW + (c4 << 2));
        int b[4];
        b[0] = pix_bin(v.x, mn, den);
        b[1] = pix_bin(v.y, mn, den);
        b[2] = pix_bin(v.z, mn, den);
        b[3] = pix_bin(v.w, mn, den);
#pragma unroll
        for (int j = 0; j < 4; j++) {
            bool hot = (b[j] == 255);
            unsigned long long m = __ballot(hot);
            if (!hot) atomicAdd(&sh[b[j]], 1u);
            if (lid == 0 && m) atomicAdd(&sh[255], (unsigned)__popcll(m));
        }
        if (STOREBINS) {
            uchar4 q;
            q.x = (unsigned char)b[0]; q.y = (unsigned char)b[1];
            q.z = (unsigned char)b[2]; q.w = (unsigned char)b[3];
            bins[(base + (size_t)r * IMW + (size_t)(c4 << 2)) >> 2] = q;
        }
    }
    __syncthreads();
    if (t < NBINS)
        hist[((size_t)img * NTPI + tile) * NBINS + t] = (float)sh[t];
}

// ---- K3: clip + redistribute + cumsum -> LUT (one block per tile) ----
__global__ __launch_bounds__(256) void k_lut(const float* __restrict__ hist,
                                             float* __restrict__ lut) {
    int t = threadIdx.x;
    int tile = blockIdx.x;
    float h = hist[(size_t)tile * NBINS + t];
    float ex = fmaxf(h - CLIP_MAXF, 0.0f);

    // block reduce sum of excess (all values integer -> exact in f32)
    float s = ex;
#pragma unroll
    for (int m = 1; m < 64; m <<= 1) s += __shfl_xor(s, m, 64);
    __shared__ float wpart[4];
    int wid = t >> 6, lid = t & 63;
    if (lid == 0) wpart[wid] = s;
    __syncthreads();
    float excess = wpart[0] + wpart[1] + wpart[2] + wpart[3];

    h = fminf(h, CLIP_MAXF);
    float redist   = floorf(excess * (1.0f / 256.0f));  // /256 exact
    float residual = excess - redist * 256.0f;
    h = h + redist + (((float)t < residual) ? 1.0f : 0.0f);

    // inclusive block scan of h over 256 bins
    float c = h;
#pragma unroll
    for (int m = 1; m < 64; m <<= 1) {
        float o = __shfl_up(c, m, 64);
        if (lid >= m) c += o;
    }
    __shared__ float wsum[4];
    if (lid == 63) wsum[wid] = c;
    __syncthreads();
    float off = 0.0f;
    for (int i = 0; i < wid; i++) off += wsum[i];
    c += off;

    float l = fminf(floorf(c * LUT_SCALE), 255.0f);
    l = fmaxf(l, 0.0f);
    lut[(size_t)tile * NBINS + t] = l;
}

// ---- K4/K5: per-quadrant (128x128) bilinear LUT application ----
// FINAL=false: per-block v min/max partials to red. FINAL=true: write normalized output.
template <bool USE_BINS, bool FINAL>
__global__ __launch_bounds__(256) void k_apply(const uchar4* __restrict__ bins,
                                               const float* __restrict__ x,
                                               const float* __restrict__ lut,
                                               const float* __restrict__ sc,
                                               float2* __restrict__ red,
                                               float4* __restrict__ out) {
    __shared__ float L[4][NBINS];
    int t = threadIdx.x;
    int qx = blockIdx.x, qy = blockIdx.y, img = blockIdx.z;
    int ty = qy >> 1, tx = qx >> 1;
    int yA = (qy & 1) ? ty : max(ty - 1, 0);
    int yB = (qy & 1) ? min(ty + 1, GH - 1) : ty;
    int xA = (qx & 1) ? tx : max(tx - 1, 0);
    int xB = (qx & 1) ? min(tx + 1, GW - 1) : tx;

    const float* lb = lut + (size_t)img * NTPI * NBINS;
    L[0][t] = lb[(size_t)(yA * GW + xA) * NBINS + t];
    L[1][t] = lb[(size_t)(yA * GW + xB) * NBINS + t];
    L[2][t] = lb[(size_t)(yB * GW + xA) * NBINS + t];
    L[3][t] = lb[(size_t)(yB * GW + xB) * NBINS + t];
    __syncthreads();

    float mn = 0.f, den = 1.f;
    if (!USE_BINS) { mn = sc[0]; den = sc[1] - mn; }
    float pmn = 0.f, oscale = 1.f;
    if (FINAL) {
        float vmn = sc[2], vmx = sc[3];
        pmn = vmn * (1.0f / 255.0f);
        float pmx = vmx * (1.0f / 255.0f);
        oscale = 1.0f / (pmx - pmn);
    }

    float vmnl = 3.4e38f, vmxl = -3.4e38f;
    int gy0 = qy << 7, gx0 = qx << 7;
    int rowoff = t >> 5;  // 0..7
    int c4 = t & 31;      // 0..31 (4-pixel groups across 128 cols)

    for (int it = 0; it < 16; ++it) {
        int r = (it << 3) + rowoff;
        int iy = gy0 + r;
        int ix0 = gx0 + (c4 << 2);
        size_t pidx = ((size_t)img * IMH + iy) * IMW + ix0;

        int b[4];
        if (USE_BINS) {
            uchar4 q = bins[pidx >> 2];
            b[0] = q.x; b[1] = q.y; b[2] = q.z; b[3] = q.w;
        } else {
            float4 v = *(const float4*)(x + pidx);
            b[0] = pix_bin(v.x, mn, den);
            b[1] = pix_bin(v.y, mn, den);
            b[2] = pix_bin(v.z, mn, den);
            b[3] = pix_bin(v.w, mn, den);
        }

        float tyf = ((float)iy + 0.5f) * (1.0f / 256.0f) - 0.5f;  // exact
        float wy = tyf - floorf(tyf);
        float4 o;
        float* op = &o.x;
#pragma unroll
        for (int j = 0; j < 4; j++) {
            float txf = ((float)(ix0 + j) + 0.5f) * (1.0f / 256.0f) - 0.5f;
            float wx = txf - floorf(txf);
            float g00 = L[0][b[j]], g01 = L[1][b[j]];
            float g10 = L[2][b[j]], g11 = L[3][b[j]];
            float v = (1.0f - wy) * ((1.0f - wx) * g00 + wx * g01) +
                      wy * ((1.0f - wx) * g10 + wx * g11);
            if (FINAL) {
                float p = v * (1.0f / 255.0f);
                op[j] = (p - pmn) * oscale;
            } else {
                vmnl = fminf(vmnl, v);
                vmxl = fmaxf(vmxl, v);
            }
        }
        if (FINAL) out[pidx >> 2] = o;
    }

    if (!FINAL) {
        block_minmax<4>(vmnl, vmxl, t);
        if (t == 0) {
            int bid = (img * 16 + qy) * 16 + qx;
            red[bid] = make_float2(vmnl, vmxl);
        }
    }
}

extern "C" void kernel_launch(void* const* d_in, const int* in_sizes, int n_in,
                              void* d_out, int out_size, void* d_ws, size_t ws_size,
                              hipStream_t stream) {
    const float* x = (const float*)d_in[0];
    float4* out = (float4*)d_out;

    unsigned char* ws = (unsigned char*)d_ws;
    float* sc     = (float*)ws;                              // 64 B
    float* hist   = (float*)(ws + 64);                       // 512 KB
    float* lut    = (float*)(ws + 64 + 512 * 1024);          // 512 KB
    float2* red1  = (float2*)(ws + 64 + 1024 * 1024);        // 8 KB (1024 float2)
    float2* red2  = (float2*)(ws + 64 + 1024 * 1024 + 8192); // 16 KB (2048 float2)
    uchar4* bins  = (uchar4*)(ws + 2 * 1024 * 1024);         // 33.5 MB

    size_t need_bins = 2 * 1024 * 1024 + (size_t)NIMG * IMH * IMW;
    bool use_bins = (ws_size >= need_bins);

    k_minmax_in<<<dim3(MM_BLOCKS), dim3(256), 0, stream>>>((const float4*)x, red1);
    k_reduce_minmax<<<dim3(1), dim3(256), 0, stream>>>(red1, MM_BLOCKS, sc, 0);

    if (use_bins)
        k_hist<true><<<dim3(NTPI, NIMG), dim3(512), 0, stream>>>(x, sc, hist, bins);
    else
        k_hist<false><<<dim3(NTPI, NIMG), dim3(512), 0, stream>>>(x, sc, hist, bins);

    k_lut<<<dim3(NIMG * NTPI), dim3(256), 0, stream>>>(hist, lut);

    dim3 qgrid(16, 16, NIMG);
    if (use_bins) {
        k_apply<true, false><<<qgrid, dim3(256), 0, stream>>>(bins, x, lut, sc, red2, out);
        k_reduce_minmax<<<dim3(1), dim3(256), 0, stream>>>(red2, APPLY_BLOCKS, sc, 2);
        k_apply<true, true><<<qgrid, dim3(256), 0, stream>>>(bins, x, lut, sc, red2, out);
    } else {
        k_apply<false, false><<<qgrid, dim3(256), 0, stream>>>(bins, x, lut, sc, red2, out);
        k_reduce_minmax<<<dim3(1), dim3(256), 0, stream>>>(red2, APPLY_BLOCKS, sc, 2);
        k_apply<false, true><<<qgrid, dim3(256), 0, stream>>>(bins, x, lut, sc, red2, out);
    }
}

// Round 3
// 121.416 us; speedup vs baseline: 1.7305x; 1.0495x over previous
//
#include <hip/hip_runtime.h>

#define NIMG 8
#define IMH 2048
#define IMW 2048
#define GH 8
#define GW 8
#define NBINS 256
#define NTPI 64                        // tiles per image
#define CLIP_MAXF 256.0f               // clip_limit*pixels//NBINS = 65536//256
#define LUT_SCALE 0.0038909912109375f  // 255/65536, exact in f32
#define LOG_GAIN_F 2.5f

#define MM_BLOCKS 2048                 // k_minmax_in grid (64 KB per block)
#define APPLY_BLOCKS (16 * 16 * NIMG)  // 2048 quadrant blocks

__device__ __forceinline__ int pix_bin(float v, float mn, float den) {
    float xn = (v - mn) / den;
    float t  = LOG_GAIN_F * log2f(1.0f + xn);
    float xc = fminf(fmaxf(t, 0.0f), 1.0f);
    int b = (int)(xc * 256.0f);
    return min(max(b, 0), 255);
}

__device__ __forceinline__ void mm4(float4 v, float& mn, float& mx) {
    mn = fminf(mn, fminf(fminf(v.x, v.y), fminf(v.z, v.w)));
    mx = fmaxf(mx, fmaxf(fmaxf(v.x, v.y), fmaxf(v.z, v.w)));
}

// block min/max; result broadcast to ALL threads
template <int NWAVES>
__device__ __forceinline__ void block_minmax_all(float& mn, float& mx, int t) {
#pragma unroll
    for (int m = 32; m >= 1; m >>= 1) {
        mn = fminf(mn, __shfl_xor(mn, m, 64));
        mx = fmaxf(mx, __shfl_xor(mx, m, 64));
    }
    __shared__ float smn[NWAVES], smx[NWAVES];
    int wid = t >> 6, lid = t & 63;
    if (lid == 0) { smn[wid] = mn; smx[wid] = mx; }
    __syncthreads();
    mn = smn[0]; mx = smx[0];
#pragma unroll
    for (int i = 1; i < NWAVES; i++) { mn = fminf(mn, smn[i]); mx = fmaxf(mx, smx[i]); }
}

// ---- K1: per-block min/max of input (64KB contiguous chunk, 4 loads in flight) ----
__global__ __launch_bounds__(256) void k_minmax_in(const float4* __restrict__ x,
                                                   float2* __restrict__ red) {
    int t = threadIdx.x;
    size_t base = (size_t)blockIdx.x * 4096 + t;   // 4096 float4 per block
    float mn = 3.4e38f, mx = -3.4e38f;
#pragma unroll
    for (int k = 0; k < 16; k += 4) {
        float4 v0 = x[base + (size_t)(k + 0) * 256];
        float4 v1 = x[base + (size_t)(k + 1) * 256];
        float4 v2 = x[base + (size_t)(k + 2) * 256];
        float4 v3 = x[base + (size_t)(k + 3) * 256];
        mm4(v0, mn, mx); mm4(v1, mn, mx); mm4(v2, mn, mx); mm4(v3, mn, mx);
    }
    block_minmax_all<4>(mn, mx, t);
    if (t == 0) red[blockIdx.x] = make_float2(mn, mx);
}

// ---- fallback-only: reduce n float2 partials -> sc[slot], sc[slot+1] ----
__global__ __launch_bounds__(256) void k_reduce_minmax(const float2* __restrict__ red, int n,
                                                       float* __restrict__ sc, int slot) {
    int t = threadIdx.x;
    float mn = 3.4e38f, mx = -3.4e38f;
    for (int i = t; i < n; i += 256) {
        float2 p = red[i];
        mn = fminf(mn, p.x);
        mx = fmaxf(mx, p.y);
    }
    block_minmax_all<4>(mn, mx, t);
    if (t == 0) { sc[slot] = mn; sc[slot + 1] = mx; }
}

// ---- K2: inline min/max reduce + per-pixel bin + per-tile hist + clip/scan -> LUT ----
// One 1024-thread block per 256x256 tile. Hot bin 255 (~68% of pixels due to
// log saturation) counted via ballot, not LDS atomic.
template <bool STOREBINS>
__global__ __launch_bounds__(1024) void k_hist(const float* __restrict__ x,
                                               const float2* __restrict__ red1,
                                               float* __restrict__ lut,
                                               uchar4* __restrict__ bins) {
    int t = threadIdx.x;

    // redundant per-block reduction of K1 partials (deterministic, L2-hot)
    float mn, mx;
    {
        float2 p0 = red1[t];
        float2 p1 = red1[t + 1024];
        mn = fminf(p0.x, p1.x);
        mx = fmaxf(p0.y, p1.y);
        block_minmax_all<16>(mn, mx, t);
    }
    float den = mx - mn;

    __shared__ unsigned sh[NBINS];
    if (t < NBINS) sh[t] = 0u;
    __syncthreads();

    int tile = blockIdx.x;  // 0..63
    int img  = blockIdx.y;  // 0..7
    int ty = tile >> 3, tx = tile & 7;

    size_t base = ((size_t)img * IMH + (size_t)ty * 256) * IMW + (size_t)tx * 256;
    const float* xt = x + base;
    int lid = t & 63;
    int rowoff = t >> 6;   // 0..15
    int c4 = t & 63;       // 0..63 float4 columns

    for (int it = 0; it < 16; ++it) {
        int r = (it << 4) + rowoff;
        float4 v = *(const float4*)(xt + (size_t)r * IMW + (c4 << 2));
        int b[4];
        b[0] = pix_bin(v.x, mn, den);
        b[1] = pix_bin(v.y, mn, den);
        b[2] = pix_bin(v.z, mn, den);
        b[3] = pix_bin(v.w, mn, den);
#pragma unroll
        for (int j = 0; j < 4; j++) {
            bool hot = (b[j] == 255);
            unsigned long long m = __ballot(hot);
            if (!hot) atomicAdd(&sh[b[j]], 1u);
            if (lid == 0 && m) atomicAdd(&sh[255], (unsigned)__popcll(m));
        }
        if (STOREBINS) {
            uchar4 q;
            q.x = (unsigned char)b[0]; q.y = (unsigned char)b[1];
            q.z = (unsigned char)b[2]; q.w = (unsigned char)b[3];
            bins[(base + (size_t)r * IMW + (size_t)(c4 << 2)) >> 2] = q;
        }
    }
    __syncthreads();

    // ---- LUT build from LDS hist (threads >=256 just participate in barriers) ----
    int wid = t >> 6;
    float h = 0.0f, ex = 0.0f;
    if (t < NBINS) {
        h = (float)sh[t];
        ex = fmaxf(h - CLIP_MAXF, 0.0f);
    }
    float s = ex;
#pragma unroll
    for (int m = 1; m < 64; m <<= 1) s += __shfl_xor(s, m, 64);
    __shared__ float wpart[16];
    if (lid == 0) wpart[wid] = s;
    __syncthreads();
    float excess = wpart[0] + wpart[1] + wpart[2] + wpart[3];

    h = fminf(h, CLIP_MAXF);
    float redist   = floorf(excess * (1.0f / 256.0f));
    float residual = excess - redist * 256.0f;
    h = h + redist + (((float)t < residual) ? 1.0f : 0.0f);

    float c = h;
#pragma unroll
    for (int m = 1; m < 64; m <<= 1) {
        float o = __shfl_up(c, m, 64);
        if (lid >= m) c += o;
    }
    __shared__ float wsum[16];
    if (lid == 63) wsum[wid] = c;
    __syncthreads();
    if (t < NBINS) {
        float off = 0.0f;
        for (int i = 0; i < wid; i++) off += wsum[i];
        c += off;
        float l = fminf(floorf(c * LUT_SCALE), 255.0f);
        l = fmaxf(l, 0.0f);
        lut[((size_t)img * NTPI + tile) * NBINS + t] = l;
    }
}

// ---- K3/K4: per-quadrant (128x128) bilinear LUT application ----
// FINAL=false: per-block v min/max partials to red2.
// FINAL=true : inline-reduce red2, write normalized output.
template <bool USE_BINS, bool FINAL>
__global__ __launch_bounds__(256) void k_apply(const uchar4* __restrict__ bins,
                                               const float* __restrict__ x,
                                               const float* __restrict__ lut,
                                               const float* __restrict__ sc,
                                               float2* __restrict__ red2,
                                               float4* __restrict__ out) {
    __shared__ float L[4][NBINS];
    int t = threadIdx.x;

    float pmn = 0.f, oscale = 1.f;
    if (FINAL) {
        float vmn = 3.4e38f, vmx = -3.4e38f;
#pragma unroll
        for (int k = 0; k < 8; k++) {
            float2 p = red2[t + k * 256];
            vmn = fminf(vmn, p.x);
            vmx = fmaxf(vmx, p.y);
        }
        block_minmax_all<4>(vmn, vmx, t);
        pmn = vmn * (1.0f / 255.0f);
        float pmx = vmx * (1.0f / 255.0f);
        oscale = 1.0f / (pmx - pmn);
    }

    int qx = blockIdx.x, qy = blockIdx.y, img = blockIdx.z;
    int ty = qy >> 1, tx = qx >> 1;
    int yA = (qy & 1) ? ty : max(ty - 1, 0);
    int yB = (qy & 1) ? min(ty + 1, GH - 1) : ty;
    int xA = (qx & 1) ? tx : max(tx - 1, 0);
    int xB = (qx & 1) ? min(tx + 1, GW - 1) : tx;

    const float* lb = lut + (size_t)img * NTPI * NBINS;
    L[0][t] = lb[(size_t)(yA * GW + xA) * NBINS + t];
    L[1][t] = lb[(size_t)(yA * GW + xB) * NBINS + t];
    L[2][t] = lb[(size_t)(yB * GW + xA) * NBINS + t];
    L[3][t] = lb[(size_t)(yB * GW + xB) * NBINS + t];
    __syncthreads();

    float mn = 0.f, den = 1.f;
    if (!USE_BINS) { mn = sc[0]; den = sc[1] - mn; }

    float vmnl = 3.4e38f, vmxl = -3.4e38f;
    int gy0 = qy << 7, gx0 = qx << 7;
    int rowoff = t >> 5;  // 0..7
    int c4 = t & 31;      // 0..31 (4-pixel groups across 128 cols)

    for (int it = 0; it < 16; ++it) {
        int r = (it << 3) + rowoff;
        int iy = gy0 + r;
        int ix0 = gx0 + (c4 << 2);
        size_t pidx = ((size_t)img * IMH + iy) * IMW + ix0;

        int b[4];
        if (USE_BINS) {
            uchar4 q = bins[pidx >> 2];
            b[0] = q.x; b[1] = q.y; b[2] = q.z; b[3] = q.w;
        } else {
            float4 v = *(const float4*)(x + pidx);
            b[0] = pix_bin(v.x, mn, den);
            b[1] = pix_bin(v.y, mn, den);
            b[2] = pix_bin(v.z, mn, den);
            b[3] = pix_bin(v.w, mn, den);
        }

        float tyf = ((float)iy + 0.5f) * (1.0f / 256.0f) - 0.5f;
        float wy = tyf - floorf(tyf);
        float4 o;
        float* op = &o.x;
#pragma unroll
        for (int j = 0; j < 4; j++) {
            float txf = ((float)(ix0 + j) + 0.5f) * (1.0f / 256.0f) - 0.5f;
            float wx = txf - floorf(txf);
            float g00 = L[0][b[j]], g01 = L[1][b[j]];
            float g10 = L[2][b[j]], g11 = L[3][b[j]];
            float v = (1.0f - wy) * ((1.0f - wx) * g00 + wx * g01) +
                      wy * ((1.0f - wx) * g10 + wx * g11);
            if (FINAL) {
                float p = v * (1.0f / 255.0f);
                op[j] = (p - pmn) * oscale;
            } else {
                vmnl = fminf(vmnl, v);
                vmxl = fmaxf(vmxl, v);
            }
        }
        if (FINAL) out[pidx >> 2] = o;
    }

    if (!FINAL) {
        block_minmax_all<4>(vmnl, vmxl, t);
        if (t == 0) {
            int bid = (img * 16 + qy) * 16 + qx;
            red2[bid] = make_float2(vmnl, vmxl);
        }
    }
}

extern "C" void kernel_launch(void* const* d_in, const int* in_sizes, int n_in,
                              void* d_out, int out_size, void* d_ws, size_t ws_size,
                              hipStream_t stream) {
    const float* x = (const float*)d_in[0];
    float4* out = (float4*)d_out;

    unsigned char* ws = (unsigned char*)d_ws;
    float* sc     = (float*)ws;                              // 64 B (fallback only)
    float* lut    = (float*)(ws + 64);                       // 512 KB
    float2* red1  = (float2*)(ws + 64 + 512 * 1024);         // 16 KB (2048 float2)
    float2* red2  = (float2*)(ws + 64 + 512 * 1024 + 16384); // 16 KB (2048 float2)
    uchar4* bins  = (uchar4*)(ws + 1024 * 1024);             // 33.5 MB

    size_t need_bins = 1024 * 1024 + (size_t)NIMG * IMH * IMW;
    bool use_bins = (ws_size >= need_bins);

    k_minmax_in<<<dim3(MM_BLOCKS), dim3(256), 0, stream>>>((const float4*)x, red1);

    dim3 qgrid(16, 16, NIMG);
    if (use_bins) {
        k_hist<true><<<dim3(NTPI, NIMG), dim3(1024), 0, stream>>>(x, red1, lut, bins);
        k_apply<true, false><<<qgrid, dim3(256), 0, stream>>>(bins, x, lut, sc, red2, out);
        k_apply<true, true><<<qgrid, dim3(256), 0, stream>>>(bins, x, lut, sc, red2, out);
    } else {
        k_reduce_minmax<<<dim3(1), dim3(256), 0, stream>>>(red1, MM_BLOCKS, sc, 0);
        k_hist<false><<<dim3(NTPI, NIMG), dim3(1024), 0, stream>>>(x, red1, lut, bins);
        k_apply<false, false><<<qgrid, dim3(256), 0, stream>>>(bins, x, lut, sc, red2, out);
        k_apply<false, true><<<qgrid, dim3(256), 0, stream>>>(bins, x, lut, sc, red2, out);
    }
}